// Round 4
// baseline (1162.448 us; speedup 1.0000x reference)
//
#include <hip/hip_runtime.h>
#include <hip/hip_bf16.h>
#include <cstdint>

typedef float     f32x4  __attribute__((ext_vector_type(4)));
typedef __bf16    bf16x8 __attribute__((ext_vector_type(8)));
typedef unsigned short u16x4 __attribute__((ext_vector_type(4)));
typedef unsigned short u16x8 __attribute__((ext_vector_type(8)));
typedef unsigned short u16;

#define DI __device__ __forceinline__

DI float b2f(u16 u) { union { unsigned int i; float f; } x; x.i = ((unsigned int)u) << 16; return x.f; }
DI u16 f2b(float f) {
  union { float f; unsigned int i; } x; x.f = f;
  return (u16)((x.i + 0x7FFFu + ((x.i >> 16) & 1u)) >> 16);   // RNE
}

// direct global->LDS async copy, 16B per lane (m97 structure)
DI void gload16(const void* g, void* l) {
  __builtin_amdgcn_global_load_lds(
      (const __attribute__((address_space(1))) unsigned int*)g,
      (__attribute__((address_space(3))) unsigned int*)l, 16, 0, 0);
}

// ---------------------------------------------------------------------------
// Transpose + fp32->bf16 convert: src (R x C) f32 row-major -> dst (C x R) bf16
// ---------------------------------------------------------------------------
__global__ __launch_bounds__(256) void tpose_f32_bf16_kernel(
    const float* __restrict__ src, u16* __restrict__ dst, int R, int C)
{
  __shared__ float tile[32][33];
  const int c0 = blockIdx.x * 32, r0 = blockIdx.y * 32;
  const int tx = threadIdx.x, ty = threadIdx.y;
  #pragma unroll
  for (int i = 0; i < 4; ++i)
    tile[ty + i * 8][tx] = src[(long)(r0 + ty + i * 8) * C + c0 + tx];
  __syncthreads();
  #pragma unroll
  for (int i = 0; i < 4; ++i)
    dst[(long)(c0 + ty + i * 8) * R + r0 + tx] = f2b(tile[tx][ty + i * 8]);
}

// ---------------------------------------------------------------------------
// LayerNorm (row of 2048) fp32 -> bf16.
// ---------------------------------------------------------------------------
__global__ __launch_bounds__(256) void ln_bf16_kernel(
    const float* __restrict__ x, const float* __restrict__ gamma,
    const float* __restrict__ beta, u16* __restrict__ out)
{
  const long row = blockIdx.x;
  const float* xr = x + row * 2048;
  const int tid = threadIdx.x;
  float4 a = *(const float4*)(xr + tid * 8);
  float4 b = *(const float4*)(xr + tid * 8 + 4);
  float s  = a.x + a.y + a.z + a.w + b.x + b.y + b.z + b.w;
  float ss = a.x*a.x + a.y*a.y + a.z*a.z + a.w*a.w
           + b.x*b.x + b.y*b.y + b.z*b.z + b.w*b.w;
  #pragma unroll
  for (int off = 1; off < 64; off <<= 1) { s += __shfl_xor(s, off); ss += __shfl_xor(ss, off); }
  __shared__ float red[8];
  if ((tid & 63) == 0) { red[tid >> 6] = s; red[4 + (tid >> 6)] = ss; }
  __syncthreads();
  s  = red[0] + red[1] + red[2] + red[3];
  ss = red[4] + red[5] + red[6] + red[7];
  const float mu = s * (1.0f / 2048.0f);
  const float rs = rsqrtf(ss * (1.0f / 2048.0f) - mu * mu + 1e-5f);
  const float v[8] = {a.x, a.y, a.z, a.w, b.x, b.y, b.z, b.w};
  u16x8 o;
  #pragma unroll
  for (int j = 0; j < 8; ++j) {
    const int col = tid * 8 + j;
    o[j] = f2b((v[j] - mu) * rs * gamma[col] + beta[col]);
  }
  *(u16x8*)(out + row * 2048 + tid * 8) = o;
}

// ---------------------------------------------------------------------------
// ksum[d_row] = sum_s kT[d_row][s]
// ---------------------------------------------------------------------------
__global__ __launch_bounds__(256) void ksum_kernel(
    const u16* __restrict__ kT, float* __restrict__ ksum)
{
  const int gw = blockIdx.x * 4 + (threadIdx.x >> 6);
  const int lane = threadIdx.x & 63;
  const u16* r = kT + (long)gw * 2048;
  float s = 0.f;
  #pragma unroll
  for (int j = 0; j < 4; ++j) {
    u16x8 v = *(const u16x8*)(r + j * 512 + lane * 8);
    #pragma unroll
    for (int e = 0; e < 8; ++e) s += b2f(v[e]);
  }
  #pragma unroll
  for (int off = 1; off < 64; off <<= 1) s += __shfl_xor(s, off);
  if (lane == 0) ksum[gw] = s;
}

// ---------------------------------------------------------------------------
// den[b][h][s] = dot(q[b][s][h*128:], ksum[b][h][:])
// ---------------------------------------------------------------------------
__global__ __launch_bounds__(256) void den_kernel(
    const u16* __restrict__ q, const float* __restrict__ ksum, float* __restrict__ den)
{
  const long m = blockIdx.x;            // b*2048 + s
  const int tid = threadIdx.x;
  const int b = (int)(m >> 11);
  const int h = tid >> 4;
  const int dl = (tid & 15) * 8;
  const u16* qr = q + m * 2048 + h * 128 + dl;
  const float* ks = ksum + ((long)b * 16 + h) * 128 + dl;
  u16x8 v = *(const u16x8*)qr;
  float s = 0.f;
  #pragma unroll
  for (int e = 0; e < 8; ++e) s += b2f(v[e]) * ks[e];
  #pragma unroll
  for (int off = 1; off < 16; off <<= 1) s += __shfl_xor(s, off);
  if ((tid & 15) == 0) den[((long)b * 16 + h) * 2048 + (m & 2047)] = s;
}

// ---------------------------------------------------------------------------
// fp32 -> bf16 elementwise
// ---------------------------------------------------------------------------
__global__ __launch_bounds__(256) void cvt_f32_bf16_kernel(
    const float* __restrict__ src, u16* __restrict__ dst, long n)
{
  long i = ((long)blockIdx.x * 256 + threadIdx.x) * 4;
  if (i >= n) return;
  float4 v = *(const float4*)(src + i);
  u16x4 o; o[0] = f2b(v.x); o[1] = f2b(v.y); o[2] = f2b(v.z); o[3] = f2b(v.w);
  *(u16x4*)(dst + i) = o;
}

// ---------------------------------------------------------------------------
// kv split-K reduce: out_bf16[i] = sum_{p<8} partial[p][i]
// ---------------------------------------------------------------------------
__global__ __launch_bounds__(256) void kvreduce_kernel(
    const float* __restrict__ p, u16* __restrict__ out)
{
  long i = ((long)blockIdx.x * 256 + threadIdx.x) * 4;
  float4 s = *(const float4*)(p + i);
  #pragma unroll
  for (int j = 1; j < 8; ++j) {
    float4 v = *(const float4*)(p + (long)j * 1048576 + i);
    s.x += v.x; s.y += v.y; s.z += v.z; s.w += v.w;
  }
  u16x4 o; o[0] = f2b(s.x); o[1] = f2b(s.y); o[2] = f2b(s.z); o[3] = f2b(s.w);
  *(u16x4*)(out + i) = o;
}

// ---------------------------------------------------------------------------
// RANK split-K reduce: out[i] = sum_{p<NP} P[p][i] (+bias[col]) (+out_old)
// ---------------------------------------------------------------------------
template<int NP, int OUTF32, int ACC>
__global__ __launch_bounds__(256) void rankreduce_kernel(
    const float* __restrict__ p, const float* __restrict__ bias, void* out)
{
  long i = ((long)blockIdx.x * 256 + threadIdx.x) * 4;
  float4 s = *(const float4*)(p + i);
  #pragma unroll
  for (int j = 1; j < NP; ++j) {
    float4 v = *(const float4*)(p + (long)j * 2097152 + i);
    s.x += v.x; s.y += v.y; s.z += v.z; s.w += v.w;
  }
  if (bias) {
    const int col = (int)(i & 255);
    s.x += bias[col]; s.y += bias[col + 1]; s.z += bias[col + 2]; s.w += bias[col + 3];
  }
  if (ACC) {
    float4 o = *(const float4*)((const float*)out + i);
    s.x += o.x; s.y += o.y; s.z += o.z; s.w += o.w;
  }
  if (OUTF32) {
    *(float4*)((float*)out + i) = s;
  } else {
    u16x4 o; o[0] = f2b(s.x); o[1] = f2b(s.y); o[2] = f2b(s.z); o[3] = f2b(s.w);
    *(u16x4*)((u16*)out + i) = o;
  }
}

// ---------------------------------------------------------------------------
// 256x256 dbuf GEMM helpers
// ---------------------------------------------------------------------------
DI void stage256(const char* Ab, const char* Bb, long ldaB, long ldbB, int k0,
                 int tid, char* As, char* Bs)
{
  #pragma unroll
  for (int i = 0; i < 4; ++i) {
    const int c = i * 512 + tid;           // 16B chunk 0..2047
    const int row = c >> 3;                // 0..255
    const int cb = (c & 7) * 16;
    gload16(Ab + (long)row * ldaB + k0 * 2 + cb, As + c * 16);
    gload16(Bb + (long)row * ldbB + k0 * 2 + cb, Bs + c * 16);
  }
}

DI void compute256(const char* As, const char* Bs, int wr, int wc, int lr, int lk,
                   f32x4 (&acc)[8][4])
{
  #pragma unroll
  for (int kk = 0; kk < 64; kk += 32) {
    bf16x8 af[8], bf[4];
    #pragma unroll
    for (int m = 0; m < 8; ++m)
      af[m] = *(const bf16x8*)(As + (wr * 128 + m * 16 + lr) * 128 + (kk + lk * 8) * 2);
    #pragma unroll
    for (int n = 0; n < 4; ++n)
      bf[n] = *(const bf16x8*)(Bs + (wc * 64 + n * 16 + lr) * 128 + (kk + lk * 8) * 2);
    #pragma unroll
    for (int m = 0; m < 8; ++m)
      #pragma unroll
      for (int n = 0; n < 4; ++n)
        acc[m][n] = __builtin_amdgcn_mfma_f32_16x16x32_bf16(af[m], bf[n], acc[m][n], 0, 0, 0);
  }
}

// ---------------------------------------------------------------------------
// 256x256-tile bt-GEMM, double-buffered prefetch (T3-minimum 2-phase):
// statically distinct LDS buffers so compiler can disambiguate gload vs ds_read.
// Requires K % 128 == 0. 512 thr = 8 waves (2Mx4N), per-wave 128x64 out.
// ---------------------------------------------------------------------------
template<int ACT, int OUTMODE, int RESID>
__global__ __launch_bounds__(512, 1) void btgemm256_kernel(
    const u16* __restrict__ A, const u16* __restrict__ Bt, void* Cv,
    const float* __restrict__ bias, const float* resid,
    int K, int lda, int ldb, int ldc)
{
  __shared__ char As0[32768], Bs0[32768], As1[32768], Bs1[32768];
  const int tid = threadIdx.x;
  const int wave = tid >> 6, lane = tid & 63;
  const int lr = lane & 15, lk = lane >> 4;
  const int wr = wave >> 2, wc = wave & 3;
  const char* Ab = (const char*)(A + (long)blockIdx.x * 256 * lda);
  const char* Bb = (const char*)(Bt + (long)blockIdx.y * 256 * ldb);
  const long ldaB = (long)lda * 2, ldbB = (long)ldb * 2;

  f32x4 acc[8][4] = {};

  stage256(Ab, Bb, ldaB, ldbB, 0, tid, As0, Bs0);
  for (int k0 = 0; k0 < K; k0 += 128) {
    __syncthreads();                        // buf0 staged (compiler drains vmcnt)
    if (k0 + 64 < K) stage256(Ab, Bb, ldaB, ldbB, k0 + 64, tid, As1, Bs1);
    compute256(As0, Bs0, wr, wc, lr, lk, acc);
    __syncthreads();                        // buf1 staged; buf0 reads done
    if (k0 + 128 < K) stage256(Ab, Bb, ldaB, ldbB, k0 + 128, tid, As0, Bs0);
    compute256(As1, Bs1, wr, wc, lr, lk, acc);
  }

  #pragma unroll
  for (int m = 0; m < 8; ++m) {
    #pragma unroll
    for (int n = 0; n < 4; ++n) {
      const int gm0 = blockIdx.x * 256 + wr * 128 + m * 16 + lk * 4;
      const int gn  = blockIdx.y * 256 + wc * 64 + n * 16 + lr;
      float v4[4];
      #pragma unroll
      for (int i = 0; i < 4; ++i) {
        float val = acc[m][n][i];
        if (bias) val += bias[gn];
        if (ACT == 1) val = (val > 0.f) ? (val + 1.f) : __builtin_exp2f(val * 1.4426950408889634f);
        if (ACT == 2) {
          const float u = val;
          const float y = 0.7978845608028654f * (u + 0.044715f * u * u * u);
          const float t = 1.0f - 2.0f / (__builtin_exp2f(y * 2.885390081777927f) + 1.0f);
          val = 0.5f * u * (1.0f + t);
        }
        if (RESID) val += resid[(long)(gm0 + i) * ldc + gn];
        v4[i] = val;
      }
      if (OUTMODE == 0) {
        u16* C = (u16*)Cv;
        #pragma unroll
        for (int i = 0; i < 4; ++i) C[(long)(gm0 + i) * ldc + gn] = f2b(v4[i]);
      } else if (OUTMODE == 1) {
        float* C = (float*)Cv;
        #pragma unroll
        for (int i = 0; i < 4; ++i) C[(long)(gm0 + i) * ldc + gn] = v4[i];
      } else {
        u16* C = (u16*)Cv;
        const int b = gm0 >> 11, s = gm0 & 2047;
        const int h = gn >> 7,  d = gn & 127;
        u16x4 p;
        p[0] = f2b(v4[0]); p[1] = f2b(v4[1]); p[2] = f2b(v4[2]); p[3] = f2b(v4[3]);
        *(u16x4*)(C + (long)((b * 16 + h) * 128 + d) * 2048 + s) = p;
      }
    }
  }
}

// ---------------------------------------------------------------------------
// 128x128 dbuf GEMM helpers
// ---------------------------------------------------------------------------
DI void stage128(const char* Ab, const char* Bb, long ldaB, long ldbB, int k0,
                 int tid, char* As, char* Bs)
{
  #pragma unroll
  for (int i = 0; i < 4; ++i) {
    const int c = i * 256 + tid;           // 16B chunk 0..1023
    const int row = c >> 3;                // 0..127
    const int cb = (c & 7) * 16;
    gload16(Ab + (long)row * ldaB + k0 * 2 + cb, As + c * 16);
    gload16(Bb + (long)row * ldbB + k0 * 2 + cb, Bs + c * 16);
  }
}

DI void compute128(const char* As, const char* Bs, int wr, int wc, int lr, int lk,
                   f32x4 (&acc)[4][4])
{
  #pragma unroll
  for (int kk = 0; kk < 64; kk += 32) {
    bf16x8 af[4], bf[4];
    #pragma unroll
    for (int m = 0; m < 4; ++m)
      af[m] = *(const bf16x8*)(As + (wr * 64 + m * 16 + lr) * 128 + (kk + lk * 8) * 2);
    #pragma unroll
    for (int n = 0; n < 4; ++n)
      bf[n] = *(const bf16x8*)(Bs + (wc * 64 + n * 16 + lr) * 128 + (kk + lk * 8) * 2);
    #pragma unroll
    for (int m = 0; m < 4; ++m)
      #pragma unroll
      for (int n = 0; n < 4; ++n)
        acc[m][n] = __builtin_amdgcn_mfma_f32_16x16x32_bf16(af[m], bf[n], acc[m][n], 0, 0, 0);
  }
}

// ---------------------------------------------------------------------------
// 128x128-tile z-batched bt-GEMM, double-buffered prefetch. K % 128 == 0.
// ---------------------------------------------------------------------------
template<int ACT, int OUTMODE, int RESID, int ACCUM, int DIVDEN>
__global__ __launch_bounds__(256) void btgemm_kernel(
    const u16* __restrict__ A, const u16* __restrict__ Bt, void* Cv,
    const float* __restrict__ bias, const float* resid, const float* __restrict__ den,
    int M, int N, int K, int lda, int ldb, int ldc, int ZMOD,
    long sAh, long sAl, long sBh, long sBl, long sCh, long sCl, long sDh, long sDl)
{
  __shared__ char As0[16384], Bs0[16384], As1[16384], Bs1[16384];
  const int tid = threadIdx.x;
  const int wave = tid >> 6, lane = tid & 63;
  const int lr = lane & 15, lk = lane >> 4;
  const int wr = wave >> 1, wc = wave & 1;
  const int z = blockIdx.z;
  const int zh = z / ZMOD, zl = z % ZMOD;
  const char* Ab = (const char*)(A + zh * sAh + zl * sAl + (long)blockIdx.x * 128 * lda);
  const char* Bb = (const char*)(Bt + zh * sBh + zl * sBl + (long)blockIdx.y * 128 * ldb);
  const long ldaB = (long)lda * 2, ldbB = (long)ldb * 2;

  f32x4 acc[4][4] = {};

  stage128(Ab, Bb, ldaB, ldbB, 0, tid, As0, Bs0);
  for (int k0 = 0; k0 < K; k0 += 128) {
    __syncthreads();
    if (k0 + 64 < K) stage128(Ab, Bb, ldaB, ldbB, k0 + 64, tid, As1, Bs1);
    compute128(As0, Bs0, wr, wc, lr, lk, acc);
    __syncthreads();
    if (k0 + 128 < K) stage128(Ab, Bb, ldaB, ldbB, k0 + 128, tid, As0, Bs0);
    compute128(As1, Bs1, wr, wc, lr, lk, acc);
  }

  const long cbase = (long)zh * sCh + (long)zl * sCl;
  #pragma unroll
  for (int m = 0; m < 4; ++m) {
    #pragma unroll
    for (int n = 0; n < 4; ++n) {
      const int gm0 = blockIdx.x * 128 + wr * 64 + m * 16 + lk * 4;
      const int gn  = blockIdx.y * 128 + wc * 64 + n * 16 + lr;
      float v4[4];
      #pragma unroll
      for (int i = 0; i < 4; ++i) {
        float val = acc[m][n][i];
        if (bias) val += bias[gn];
        if (ACT == 1) val = (val > 0.f) ? (val + 1.f) : __builtin_exp2f(val * 1.4426950408889634f);
        if (ACT == 2) {
          const float u = val;
          const float y = 0.7978845608028654f * (u + 0.044715f * u * u * u);
          const float t = 1.0f - 2.0f / (__builtin_exp2f(y * 2.885390081777927f) + 1.0f);
          val = 0.5f * u * (1.0f + t);
        }
        if (DIVDEN) val = val / (den[(long)zh * sDh + (long)zl * sDl + gm0 + i] + 1e-6f);
        if (RESID) val += resid[cbase + (long)(gm0 + i) * ldc + gn];
        if (ACCUM) val += ((const float*)Cv)[cbase + (long)(gm0 + i) * ldc + gn];
        v4[i] = val;
      }
      if (OUTMODE == 0) {
        u16* C = (u16*)Cv;
        #pragma unroll
        for (int i = 0; i < 4; ++i) C[cbase + (long)(gm0 + i) * ldc + gn] = f2b(v4[i]);
      } else if (OUTMODE == 1) {
        float* C = (float*)Cv;
        #pragma unroll
        for (int i = 0; i < 4; ++i) C[cbase + (long)(gm0 + i) * ldc + gn] = v4[i];
      } else {
        u16* C = (u16*)Cv;
        const int b = gm0 >> 11, s = gm0 & 2047;
        const int h = gn >> 7,  d = gn & 127;
        u16x4 p;
        p[0] = f2b(v4[0]); p[1] = f2b(v4[1]); p[2] = f2b(v4[2]); p[3] = f2b(v4[3]);
        *(u16x4*)(C + (long)((b * 16 + h) * 128 + d) * 2048 + s) = p;
      }
    }
  }
}

// ---------------------------------------------------------------------------
extern "C" void kernel_launch(void* const* d_in, const int* in_sizes, int n_in,
                              void* d_out, int out_size, void* d_ws, size_t ws_size,
                              hipStream_t stream) {
  const float* x   = (const float*)d_in[0];
  const float* Wq  = (const float*)d_in[1];
  const float* bq  = (const float*)d_in[2];
  const float* Wk  = (const float*)d_in[3];
  const float* bk  = (const float*)d_in[4];
  const float* Wv  = (const float*)d_in[5];
  const float* bv  = (const float*)d_in[6];
  const float* Wo  = (const float*)d_in[7];
  const float* bo  = (const float*)d_in[8];
  const float* g1  = (const float*)d_in[9];
  const float* be1 = (const float*)d_in[10];
  const float* g2  = (const float*)d_in[11];
  const float* be2 = (const float*)d_in[12];
  const float* W1  = (const float*)d_in[13];
  const float* b1  = (const float*)d_in[14];
  const float* W2  = (const float*)d_in[15];
  const float* b2  = (const float*)d_in[16];
  const float* W3  = (const float*)d_in[17];
  const float* b3  = (const float*)d_in[18];
  const float* W4  = (const float*)d_in[19];
  const float* b4  = (const float*)d_in[20];
  float* xout = (float*)d_out;
  char* ws = (char*)d_ws;

  // workspace layout (bytes); total ~172.6 MB
  constexpr long DD2 = 2048L * 2048 * 2;          // 8 MB
  constexpr size_t oWqT = 0;
  constexpr size_t oWkT = oWqT + DD2;
  constexpr size_t oWvT = oWkT + DD2;
  constexpr size_t oWoT = oWvT + DD2;
  constexpr size_t oW1T = oWoT + DD2;             // 256x2048 bf16 (1 MB)
  constexpr size_t oW2T = oW1T + 256L * 2048 * 2; // 8192x256 bf16 (4 MB)
  constexpr size_t oW3T = oW2T + 8192L * 256 * 2; // 256x8192 bf16 (4 MB)
  constexpr size_t oW4T = oW3T + 256L * 8192 * 2; // 2048x256 bf16 (1 MB)
  constexpr size_t oH1  = oW4T + 2048L * 256 * 2; // 32MB: h1 / kvpart / attnN / rank-partials
  constexpr size_t oQ   = oH1 + 8192L * 2048 * 2; // 32MB: q / h2 / t3f+t3b
  constexpr size_t oKT  = oQ  + 8192L * 2048 * 2; // 32MB: kT / t1
  constexpr size_t oVT  = oKT + 8192L * 2048 * 2; // 32MB: vT / t2chunk
  constexpr size_t oKVT = oVT + 8192L * 2048 * 2; // 64x128x128 bf16 (2MB)
  constexpr size_t oKS  = oKVT + 64L * 128 * 128 * 2;
  constexpr size_t oDEN = oKS + 64L * 128 * 4;

  u16* WqT = (u16*)(ws + oWqT);
  u16* WkT = (u16*)(ws + oWkT);
  u16* WvT = (u16*)(ws + oWvT);
  u16* WoT = (u16*)(ws + oWoT);
  u16* W1T = (u16*)(ws + oW1T);
  u16* W2T = (u16*)(ws + oW2T);
  u16* W3T = (u16*)(ws + oW3T);
  u16* W4T = (u16*)(ws + oW4T);
  u16* H1    = (u16*)(ws + oH1);    // h1; kv partials; attnN; rank split-K partials
  float* KVP = (float*)(ws + oH1);
  float* RP  = (float*)(ws + oH1);  // rank partials [NP][8192][256] f32
  u16* Qb    = (u16*)(ws + oQ);     // q; h2
  float* T3f = (float*)(ws + oQ);   // after h2 dead: t3 f32 (8MB)
  u16* T3B   = (u16*)(ws + oQ + 8L * 1024 * 1024); // t3 bf16 (4MB)
  u16* KT    = (u16*)(ws + oKT);    // kT; then t1
  u16* T1    = (u16*)(ws + oKT);
  u16* VT    = (u16*)(ws + oVT);    // vT; then t2 chunk
  u16* T2C   = (u16*)(ws + oVT);
  u16* KVT = (u16*)(ws + oKVT);
  float* KS  = (float*)(ws + oKS);
  float* DEN = (float*)(ws + oDEN);
  u16* H2  = Qb;

  const dim3 tb32(32, 8);
  tpose_f32_bf16_kernel<<<dim3(64, 64), tb32, 0, stream>>>(Wq, WqT, 2048, 2048);
  tpose_f32_bf16_kernel<<<dim3(64, 64), tb32, 0, stream>>>(Wk, WkT, 2048, 2048);
  tpose_f32_bf16_kernel<<<dim3(64, 64), tb32, 0, stream>>>(Wv, WvT, 2048, 2048);
  tpose_f32_bf16_kernel<<<dim3(64, 64), tb32, 0, stream>>>(Wo, WoT, 2048, 2048);
  tpose_f32_bf16_kernel<<<dim3(8, 64),  tb32, 0, stream>>>(W1, W1T, 2048, 256);
  tpose_f32_bf16_kernel<<<dim3(256, 8), tb32, 0, stream>>>(W2, W2T, 256, 8192);
  tpose_f32_bf16_kernel<<<dim3(8, 256), tb32, 0, stream>>>(W3, W3T, 8192, 256);
  tpose_f32_bf16_kernel<<<dim3(64, 8),  tb32, 0, stream>>>(W4, W4T, 256, 2048);

  // h1 = LN1(x)
  ln_bf16_kernel<<<8192, 256, 0, stream>>>(x, g1, be1, H1);

  // q,k,v projections (256^2 tile, grid 32x8 = 256 blocks)
  btgemm256_kernel<1, 0, 0><<<dim3(32, 8), 512, 0, stream>>>(
      H1, WqT, Qb, bq, nullptr, 2048, 2048, 2048, 2048);
  btgemm256_kernel<1, 2, 0><<<dim3(32, 8), 512, 0, stream>>>(
      H1, WkT, KT, bk, nullptr, 2048, 2048, 2048, 2048);
  btgemm256_kernel<0, 2, 0><<<dim3(32, 8), 512, 0, stream>>>(
      H1, WvT, VT, bv, nullptr, 2048, 2048, 2048, 2048);

  // ksum over S, den = q.ksum
  ksum_kernel<<<2048, 256, 0, stream>>>(KT, KS);
  den_kernel<<<8192, 256, 0, stream>>>(Qb, KS, DEN);

  // kv split-K (z = head*8 + K-chunk of 256) -> f32 partials -> reduce
  btgemm_kernel<0, 1, 0, 0, 0><<<dim3(1, 1, 512), 256, 0, stream>>>(
      VT, KT, KVP, nullptr, nullptr, nullptr, 128, 128, 256, 2048, 2048, 128, 8,
      262144, 256, 262144, 256, 16384, 1048576, 0, 0);
  kvreduce_kernel<<<1024, 256, 0, stream>>>(KVP, KVT);

  // num = q @ kvT ; /(den+eps) -> attnN (bf16, (B,S,D), into H1 region)
  btgemm_kernel<0, 0, 0, 0, 1><<<dim3(16, 1, 64), 256, 0, stream>>>(
      Qb, KVT, H1, nullptr, nullptr, DEN, 2048, 128, 128, 2048, 128, 2048, 16,
      4194304, 128, 262144, 16384, 4194304, 128, 32768, 2048);

  // x2 = x + attnN@Wo + bo -> d_out (f32)
  btgemm256_kernel<0, 1, 1><<<dim3(32, 8), 512, 0, stream>>>(
      H1, WoT, xout, bo, x, 2048, 2048, 2048, 2048);

  // h2 = LN2(x2)
  ln_bf16_kernel<<<8192, 256, 0, stream>>>(xout, g2, be2, H2);

  // t1 = h2@W1 + b1 : split-K x4 (K-sub 512) -> reduce bf16
  btgemm_kernel<0, 1, 0, 0, 0><<<dim3(64, 2, 4), 256, 0, stream>>>(
      H2, W1T, RP, nullptr, nullptr, nullptr, 8192, 256, 512, 2048, 2048, 256, 4,
      0, 512, 0, 512, 0, 2097152, 0, 0);
  rankreduce_kernel<4, 0, 0><<<2048, 256, 0, stream>>>(RP, b1, T1);

  // FFN middle, 4 HID-chunks of 2048:
  //   t2c = gelu(t1@W2c+b2c) [256^2]; t3f (+)= t2c@W3c [split-K x2 + reduce]
  for (int c = 0; c < 4; ++c) {
    btgemm256_kernel<2, 0, 0><<<dim3(32, 8), 512, 0, stream>>>(
        T1, W2T + (long)c * 2048 * 256, T2C, b2 + c * 2048, nullptr,
        256, 256, 256, 2048);
    btgemm_kernel<0, 1, 0, 0, 0><<<dim3(64, 2, 2), 256, 0, stream>>>(
        T2C, W3T + (long)c * 2048, RP, nullptr, nullptr, nullptr,
        8192, 256, 1024, 2048, 8192, 256, 2,
        0, 1024, 0, 1024, 0, 2097152, 0, 0);
    if (c == 0)
      rankreduce_kernel<2, 1, 0><<<2048, 256, 0, stream>>>(RP, b3, T3f);
    else
      rankreduce_kernel<2, 1, 1><<<2048, 256, 0, stream>>>(RP, nullptr, T3f);
  }

  // t3 -> bf16
  cvt_f32_bf16_kernel<<<2048, 256, 0, stream>>>(T3f, T3B, 8192L * 256);

  // out = x2 + t3@W4 + b4   (resid = d_out itself)
  btgemm256_kernel<0, 1, 1><<<dim3(32, 8), 512, 0, stream>>>(
      T3B, W4T, xout, b4, xout, 256, 256, 256, 2048);
}

// Round 5
// 962.953 us; speedup vs baseline: 1.2072x; 1.2072x over previous
//
#include <hip/hip_runtime.h>
#include <hip/hip_bf16.h>
#include <cstdint>

typedef float     f32x4  __attribute__((ext_vector_type(4)));
typedef __bf16    bf16x8 __attribute__((ext_vector_type(8)));
typedef unsigned short u16x4 __attribute__((ext_vector_type(4)));
typedef unsigned short u16x8 __attribute__((ext_vector_type(8)));
typedef unsigned short u16;

#define DI __device__ __forceinline__

DI float b2f(u16 u) { union { unsigned int i; float f; } x; x.i = ((unsigned int)u) << 16; return x.f; }
DI u16 f2b(float f) {
  union { float f; unsigned int i; } x; x.f = f;
  return (u16)((x.i + 0x7FFFu + ((x.i >> 16) & 1u)) >> 16);   // RNE
}

// direct global->LDS async copy, 16B per lane
DI void gload16(const void* g, void* l) {
  __builtin_amdgcn_global_load_lds(
      (const __attribute__((address_space(1))) unsigned int*)g,
      (__attribute__((address_space(3))) unsigned int*)l, 16, 0, 0);
}

// ---------------------------------------------------------------------------
// Transpose + fp32->bf16 convert: src (R x C) f32 row-major -> dst (C x R) bf16
// ---------------------------------------------------------------------------
__global__ __launch_bounds__(256) void tpose_f32_bf16_kernel(
    const float* __restrict__ src, u16* __restrict__ dst, int R, int C)
{
  __shared__ float tile[32][33];
  const int c0 = blockIdx.x * 32, r0 = blockIdx.y * 32;
  const int tx = threadIdx.x, ty = threadIdx.y;
  #pragma unroll
  for (int i = 0; i < 4; ++i)
    tile[ty + i * 8][tx] = src[(long)(r0 + ty + i * 8) * C + c0 + tx];
  __syncthreads();
  #pragma unroll
  for (int i = 0; i < 4; ++i)
    dst[(long)(c0 + ty + i * 8) * R + r0 + tx] = f2b(tile[tx][ty + i * 8]);
}

// ---------------------------------------------------------------------------
// LayerNorm (row of 2048) fp32 -> bf16.
// ---------------------------------------------------------------------------
__global__ __launch_bounds__(256) void ln_bf16_kernel(
    const float* __restrict__ x, const float* __restrict__ gamma,
    const float* __restrict__ beta, u16* __restrict__ out)
{
  const long row = blockIdx.x;
  const float* xr = x + row * 2048;
  const int tid = threadIdx.x;
  float4 a = *(const float4*)(xr + tid * 8);
  float4 b = *(const float4*)(xr + tid * 8 + 4);
  float s  = a.x + a.y + a.z + a.w + b.x + b.y + b.z + b.w;
  float ss = a.x*a.x + a.y*a.y + a.z*a.z + a.w*a.w
           + b.x*b.x + b.y*b.y + b.z*b.z + b.w*b.w;
  #pragma unroll
  for (int off = 1; off < 64; off <<= 1) { s += __shfl_xor(s, off); ss += __shfl_xor(ss, off); }
  __shared__ float red[8];
  if ((tid & 63) == 0) { red[tid >> 6] = s; red[4 + (tid >> 6)] = ss; }
  __syncthreads();
  s  = red[0] + red[1] + red[2] + red[3];
  ss = red[4] + red[5] + red[6] + red[7];
  const float mu = s * (1.0f / 2048.0f);
  const float rs = rsqrtf(ss * (1.0f / 2048.0f) - mu * mu + 1e-5f);
  const float v[8] = {a.x, a.y, a.z, a.w, b.x, b.y, b.z, b.w};
  u16x8 o;
  #pragma unroll
  for (int j = 0; j < 8; ++j) {
    const int col = tid * 8 + j;
    o[j] = f2b((v[j] - mu) * rs * gamma[col] + beta[col]);
  }
  *(u16x8*)(out + row * 2048 + tid * 8) = o;
}

// ---------------------------------------------------------------------------
// ksum[d_row] = sum_s kT[d_row][s]
// ---------------------------------------------------------------------------
__global__ __launch_bounds__(256) void ksum_kernel(
    const u16* __restrict__ kT, float* __restrict__ ksum)
{
  const int gw = blockIdx.x * 4 + (threadIdx.x >> 6);
  const int lane = threadIdx.x & 63;
  const u16* r = kT + (long)gw * 2048;
  float s = 0.f;
  #pragma unroll
  for (int j = 0; j < 4; ++j) {
    u16x8 v = *(const u16x8*)(r + j * 512 + lane * 8);
    #pragma unroll
    for (int e = 0; e < 8; ++e) s += b2f(v[e]);
  }
  #pragma unroll
  for (int off = 1; off < 64; off <<= 1) s += __shfl_xor(s, off);
  if (lane == 0) ksum[gw] = s;
}

// ---------------------------------------------------------------------------
// den[b][h][s] = dot(q[b][s][h*128:], ksum[b][h][:])
// ---------------------------------------------------------------------------
__global__ __launch_bounds__(256) void den_kernel(
    const u16* __restrict__ q, const float* __restrict__ ksum, float* __restrict__ den)
{
  const long m = blockIdx.x;            // b*2048 + s
  const int tid = threadIdx.x;
  const int b = (int)(m >> 11);
  const int h = tid >> 4;
  const int dl = (tid & 15) * 8;
  const u16* qr = q + m * 2048 + h * 128 + dl;
  const float* ks = ksum + ((long)b * 16 + h) * 128 + dl;
  u16x8 v = *(const u16x8*)qr;
  float s = 0.f;
  #pragma unroll
  for (int e = 0; e < 8; ++e) s += b2f(v[e]) * ks[e];
  #pragma unroll
  for (int off = 1; off < 16; off <<= 1) s += __shfl_xor(s, off);
  if ((tid & 15) == 0) den[((long)b * 16 + h) * 2048 + (m & 2047)] = s;
}

// ---------------------------------------------------------------------------
// fp32 -> bf16 elementwise
// ---------------------------------------------------------------------------
__global__ __launch_bounds__(256) void cvt_f32_bf16_kernel(
    const float* __restrict__ src, u16* __restrict__ dst, long n)
{
  long i = ((long)blockIdx.x * 256 + threadIdx.x) * 4;
  if (i >= n) return;
  float4 v = *(const float4*)(src + i);
  u16x4 o; o[0] = f2b(v.x); o[1] = f2b(v.y); o[2] = f2b(v.z); o[3] = f2b(v.w);
  *(u16x4*)(dst + i) = o;
}

// ---------------------------------------------------------------------------
// kv split-K reduce: out_bf16[i] = sum_{p<8} partial[p][i]
// ---------------------------------------------------------------------------
__global__ __launch_bounds__(256) void kvreduce_kernel(
    const float* __restrict__ p, u16* __restrict__ out)
{
  long i = ((long)blockIdx.x * 256 + threadIdx.x) * 4;
  float4 s = *(const float4*)(p + i);
  #pragma unroll
  for (int j = 1; j < 8; ++j) {
    float4 v = *(const float4*)(p + (long)j * 1048576 + i);
    s.x += v.x; s.y += v.y; s.z += v.z; s.w += v.w;
  }
  u16x4 o; o[0] = f2b(s.x); o[1] = f2b(s.y); o[2] = f2b(s.z); o[3] = f2b(s.w);
  *(u16x4*)(out + i) = o;
}

// ---------------------------------------------------------------------------
// RANK split-K reduce: out[i] = sum_{p<NP} P[p][i] (+bias[col]) (+out_old)
// ---------------------------------------------------------------------------
template<int NP, int OUTF32, int ACC>
__global__ __launch_bounds__(256) void rankreduce_kernel(
    const float* __restrict__ p, const float* __restrict__ bias, void* out)
{
  long i = ((long)blockIdx.x * 256 + threadIdx.x) * 4;
  float4 s = *(const float4*)(p + i);
  #pragma unroll
  for (int j = 1; j < NP; ++j) {
    float4 v = *(const float4*)(p + (long)j * 2097152 + i);
    s.x += v.x; s.y += v.y; s.z += v.z; s.w += v.w;
  }
  if (bias) {
    const int col = (int)(i & 255);
    s.x += bias[col]; s.y += bias[col + 1]; s.z += bias[col + 2]; s.w += bias[col + 3];
  }
  if (ACC) {
    float4 o = *(const float4*)((const float*)out + i);
    s.x += o.x; s.y += o.y; s.z += o.z; s.w += o.w;
  }
  if (OUTF32) {
    *(float4*)((float*)out + i) = s;
  } else {
    u16x4 o; o[0] = f2b(s.x); o[1] = f2b(s.y); o[2] = f2b(s.z); o[3] = f2b(s.w);
    *(u16x4*)((u16*)out + i) = o;
  }
}

// ---------------------------------------------------------------------------
// 256x256-tile bt-GEMM with K-slice ring pipeline (T3+T4 counted vmcnt):
//   4 LDS regions x (A[256x32] + B[256x32] bf16) = 128 KB ring.
//   Prologue stages slices 0..2; steady state keeps 2 slices (8 gloads/wave)
//   in flight ACROSS the per-slice barrier: s_waitcnt vmcnt(8), never 0.
//   Stage of slice s+3 reuses region (s-1)&3 (all readers passed barrier).
//   Requires K % 32 == 0 and K >= 96. 512 thr = 8 waves (2M x 4N).
// ---------------------------------------------------------------------------
template<int ACT, int OUTMODE, int RESID>
__global__ __launch_bounds__(512, 1) void btgemm256_kernel(
    const u16* __restrict__ A, const u16* __restrict__ Bt, void* Cv,
    const float* __restrict__ bias, const float* resid,
    int K, int lda, int ldb, int ldc)
{
  __shared__ char lds[131072];
  const int tid = threadIdx.x;
  const int wave = tid >> 6, lane = tid & 63;
  const int lr = lane & 15, lk = lane >> 4;
  const int wr = wave >> 2, wc = wave & 3;
  const char* Ab = (const char*)(A + (long)blockIdx.x * 256 * lda);
  const char* Bb = (const char*)(Bt + (long)blockIdx.y * 256 * ldb);
  const long ldaB = (long)lda * 2, ldbB = (long)ldb * 2;

  // staging constants: 2 chunks per operand per thread (1024 x 16B per operand)
  long srcA[2], srcB[2];
  int  dstO[2];
  #pragma unroll
  for (int j = 0; j < 2; ++j) {
    const int c = j * 512 + tid;            // chunk 0..1023
    const int row = c >> 2;                 // 0..255
    const int cb = (c & 3) * 16;            // byte col in 64B row
    const int swz = cb ^ ((row & 3) << 4);  // involutive pre-swizzle (rule #21)
    srcA[j] = (long)row * ldaB + swz;
    srcB[j] = (long)row * ldbB + swz;
    dstO[j] = c * 16;                        // linear LDS dest
  }
  // read-side swizzled k-offset (lane-constant)
  const int swzR = (lk * 16) ^ ((lr & 3) << 4);

  f32x4 acc[8][4] = {};

  #define STAGE_SL(s)                                                      \
    {                                                                      \
      char* R_ = lds + ((s) & 3) * 32768;                                  \
      const long colB_ = (long)(s) * 64;                                   \
      _Pragma("unroll")                                                    \
      for (int j = 0; j < 2; ++j) {                                        \
        gload16(Ab + srcA[j] + colB_, R_ + dstO[j]);                       \
        gload16(Bb + srcB[j] + colB_, R_ + 16384 + dstO[j]);               \
      }                                                                    \
    }

  #define SLICE_BODY(s, dostage)                                           \
    {                                                                      \
      const char* R_ = lds + ((s) & 3) * 32768;                            \
      bf16x8 af[8], bf[4];                                                 \
      _Pragma("unroll")                                                    \
      for (int m = 0; m < 8; ++m)                                          \
        af[m] = *(const bf16x8*)(R_ + (wr * 128 + m * 16 + lr) * 64 + swzR);\
      _Pragma("unroll")                                                    \
      for (int n = 0; n < 4; ++n)                                          \
        bf[n] = *(const bf16x8*)(R_ + 16384 + (wc * 64 + n * 16 + lr) * 64 + swzR);\
      if (dostage) STAGE_SL((s) + 3);                                      \
      __builtin_amdgcn_s_setprio(1);                                       \
      _Pragma("unroll")                                                    \
      for (int m = 0; m < 8; ++m)                                          \
        _Pragma("unroll")                                                  \
        for (int n = 0; n < 4; ++n)                                        \
          acc[m][n] = __builtin_amdgcn_mfma_f32_16x16x32_bf16(af[m], bf[n], acc[m][n], 0, 0, 0);\
      __builtin_amdgcn_s_setprio(0);                                       \
    }

  const int S = K >> 5;                     // K/32 slices
  STAGE_SL(0); STAGE_SL(1); STAGE_SL(2);    // 12 loads/wave in flight
  for (int s = 0; s < S - 2; ++s) {
    asm volatile("s_waitcnt vmcnt(8)" ::: "memory");   // slice s landed
    __builtin_amdgcn_s_barrier();
    __builtin_amdgcn_sched_barrier(0);
    SLICE_BODY(s, (s + 3 < S));
  }
  asm volatile("s_waitcnt vmcnt(4)" ::: "memory");
  __builtin_amdgcn_s_barrier();
  __builtin_amdgcn_sched_barrier(0);
  SLICE_BODY(S - 2, false);
  asm volatile("s_waitcnt vmcnt(0)" ::: "memory");
  __builtin_amdgcn_s_barrier();
  __builtin_amdgcn_sched_barrier(0);
  SLICE_BODY(S - 1, false);
  #undef STAGE_SL
  #undef SLICE_BODY

  #pragma unroll
  for (int m = 0; m < 8; ++m) {
    #pragma unroll
    for (int n = 0; n < 4; ++n) {
      const int gm0 = blockIdx.x * 256 + wr * 128 + m * 16 + lk * 4;
      const int gn  = blockIdx.y * 256 + wc * 64 + n * 16 + lr;
      float v4[4];
      #pragma unroll
      for (int i = 0; i < 4; ++i) {
        float val = acc[m][n][i];
        if (bias) val += bias[gn];
        if (ACT == 1) val = (val > 0.f) ? (val + 1.f) : __builtin_exp2f(val * 1.4426950408889634f);
        if (ACT == 2) {
          const float u = val;
          const float y = 0.7978845608028654f * (u + 0.044715f * u * u * u);
          const float t = 1.0f - 2.0f / (__builtin_exp2f(y * 2.885390081777927f) + 1.0f);
          val = 0.5f * u * (1.0f + t);
        }
        if (RESID) val += resid[(long)(gm0 + i) * ldc + gn];
        v4[i] = val;
      }
      if (OUTMODE == 0) {
        u16* C = (u16*)Cv;
        #pragma unroll
        for (int i = 0; i < 4; ++i) C[(long)(gm0 + i) * ldc + gn] = f2b(v4[i]);
      } else if (OUTMODE == 1) {
        float* C = (float*)Cv;
        #pragma unroll
        for (int i = 0; i < 4; ++i) C[(long)(gm0 + i) * ldc + gn] = v4[i];
      } else {
        u16* C = (u16*)Cv;
        const int b = gm0 >> 11, s = gm0 & 2047;
        const int h = gn >> 7,  d = gn & 127;
        u16x4 p;
        p[0] = f2b(v4[0]); p[1] = f2b(v4[1]); p[2] = f2b(v4[2]); p[3] = f2b(v4[3]);
        *(u16x4*)(C + (long)((b * 16 + h) * 128 + d) * 2048 + s) = p;
      }
    }
  }
}

// ---------------------------------------------------------------------------
// 128x128 dbuf GEMM helpers (tail kernels; >1 block/CU so dbuf overlaps)
// ---------------------------------------------------------------------------
DI void stage128(const char* Ab, const char* Bb, long ldaB, long ldbB, int k0,
                 int tid, char* As, char* Bs)
{
  #pragma unroll
  for (int i = 0; i < 4; ++i) {
    const int c = i * 256 + tid;           // 16B chunk 0..1023
    const int row = c >> 3;                // 0..127
    const int cb = (c & 7) * 16;
    gload16(Ab + (long)row * ldaB + k0 * 2 + cb, As + c * 16);
    gload16(Bb + (long)row * ldbB + k0 * 2 + cb, Bs + c * 16);
  }
}

DI void compute128(const char* As, const char* Bs, int wr, int wc, int lr, int lk,
                   f32x4 (&acc)[4][4])
{
  #pragma unroll
  for (int kk = 0; kk < 64; kk += 32) {
    bf16x8 af[4], bf[4];
    #pragma unroll
    for (int m = 0; m < 4; ++m)
      af[m] = *(const bf16x8*)(As + (wr * 64 + m * 16 + lr) * 128 + (kk + lk * 8) * 2);
    #pragma unroll
    for (int n = 0; n < 4; ++n)
      bf[n] = *(const bf16x8*)(Bs + (wc * 64 + n * 16 + lr) * 128 + (kk + lk * 8) * 2);
    #pragma unroll
    for (int m = 0; m < 4; ++m)
      #pragma unroll
      for (int n = 0; n < 4; ++n)
        acc[m][n] = __builtin_amdgcn_mfma_f32_16x16x32_bf16(af[m], bf[n], acc[m][n], 0, 0, 0);
  }
}

// ---------------------------------------------------------------------------
// 128x128-tile z-batched bt-GEMM, double-buffered prefetch. K % 128 == 0 or 128.
// ---------------------------------------------------------------------------
template<int ACT, int OUTMODE, int RESID, int ACCUM, int DIVDEN>
__global__ __launch_bounds__(256) void btgemm_kernel(
    const u16* __restrict__ A, const u16* __restrict__ Bt, void* Cv,
    const float* __restrict__ bias, const float* resid, const float* __restrict__ den,
    int M, int N, int K, int lda, int ldb, int ldc, int ZMOD,
    long sAh, long sAl, long sBh, long sBl, long sCh, long sCl, long sDh, long sDl)
{
  __shared__ char As0[16384], Bs0[16384], As1[16384], Bs1[16384];
  const int tid = threadIdx.x;
  const int wave = tid >> 6, lane = tid & 63;
  const int lr = lane & 15, lk = lane >> 4;
  const int wr = wave >> 1, wc = wave & 1;
  const int z = blockIdx.z;
  const int zh = z / ZMOD, zl = z % ZMOD;
  const char* Ab = (const char*)(A + zh * sAh + zl * sAl + (long)blockIdx.x * 128 * lda);
  const char* Bb = (const char*)(Bt + zh * sBh + zl * sBl + (long)blockIdx.y * 128 * ldb);
  const long ldaB = (long)lda * 2, ldbB = (long)ldb * 2;

  f32x4 acc[4][4] = {};

  stage128(Ab, Bb, ldaB, ldbB, 0, tid, As0, Bs0);
  for (int k0 = 0; k0 < K; k0 += 128) {
    __syncthreads();
    if (k0 + 64 < K) stage128(Ab, Bb, ldaB, ldbB, k0 + 64, tid, As1, Bs1);
    compute128(As0, Bs0, wr, wc, lr, lk, acc);
    __syncthreads();
    if (k0 + 128 < K) stage128(Ab, Bb, ldaB, ldbB, k0 + 128, tid, As0, Bs0);
    if (k0 + 64 < K) compute128(As1, Bs1, wr, wc, lr, lk, acc);
  }

  const long cbase = (long)zh * sCh + (long)zl * sCl;
  #pragma unroll
  for (int m = 0; m < 4; ++m) {
    #pragma unroll
    for (int n = 0; n < 4; ++n) {
      const int gm0 = blockIdx.x * 128 + wr * 64 + m * 16 + lk * 4;
      const int gn  = blockIdx.y * 128 + wc * 64 + n * 16 + lr;
      float v4[4];
      #pragma unroll
      for (int i = 0; i < 4; ++i) {
        float val = acc[m][n][i];
        if (bias) val += bias[gn];
        if (ACT == 1) val = (val > 0.f) ? (val + 1.f) : __builtin_exp2f(val * 1.4426950408889634f);
        if (ACT == 2) {
          const float u = val;
          const float y = 0.7978845608028654f * (u + 0.044715f * u * u * u);
          const float t = 1.0f - 2.0f / (__builtin_exp2f(y * 2.885390081777927f) + 1.0f);
          val = 0.5f * u * (1.0f + t);
        }
        if (DIVDEN) val = val / (den[(long)zh * sDh + (long)zl * sDl + gm0 + i] + 1e-6f);
        if (RESID) val += resid[cbase + (long)(gm0 + i) * ldc + gn];
        if (ACCUM) val += ((const float*)Cv)[cbase + (long)(gm0 + i) * ldc + gn];
        v4[i] = val;
      }
      if (OUTMODE == 0) {
        u16* C = (u16*)Cv;
        #pragma unroll
        for (int i = 0; i < 4; ++i) C[cbase + (long)(gm0 + i) * ldc + gn] = f2b(v4[i]);
      } else if (OUTMODE == 1) {
        float* C = (float*)Cv;
        #pragma unroll
        for (int i = 0; i < 4; ++i) C[cbase + (long)(gm0 + i) * ldc + gn] = v4[i];
      } else {
        u16* C = (u16*)Cv;
        const int b = gm0 >> 11, s = gm0 & 2047;
        const int h = gn >> 7,  d = gn & 127;
        u16x4 p;
        p[0] = f2b(v4[0]); p[1] = f2b(v4[1]); p[2] = f2b(v4[2]); p[3] = f2b(v4[3]);
        *(u16x4*)(C + (long)((b * 16 + h) * 128 + d) * 2048 + s) = p;
      }
    }
  }
}

// ---------------------------------------------------------------------------
extern "C" void kernel_launch(void* const* d_in, const int* in_sizes, int n_in,
                              void* d_out, int out_size, void* d_ws, size_t ws_size,
                              hipStream_t stream) {
  const float* x   = (const float*)d_in[0];
  const float* Wq  = (const float*)d_in[1];
  const float* bq  = (const float*)d_in[2];
  const float* Wk  = (const float*)d_in[3];
  const float* bk  = (const float*)d_in[4];
  const float* Wv  = (const float*)d_in[5];
  const float* bv  = (const float*)d_in[6];
  const float* Wo  = (const float*)d_in[7];
  const float* bo  = (const float*)d_in[8];
  const float* g1  = (const float*)d_in[9];
  const float* be1 = (const float*)d_in[10];
  const float* g2  = (const float*)d_in[11];
  const float* be2 = (const float*)d_in[12];
  const float* W1  = (const float*)d_in[13];
  const float* b1  = (const float*)d_in[14];
  const float* W2  = (const float*)d_in[15];
  const float* b2  = (const float*)d_in[16];
  const float* W3  = (const float*)d_in[17];
  const float* b3  = (const float*)d_in[18];
  const float* W4  = (const float*)d_in[19];
  const float* b4  = (const float*)d_in[20];
  float* xout = (float*)d_out;
  char* ws = (char*)d_ws;

  // workspace layout (bytes); total ~172.6 MB
  constexpr long DD2 = 2048L * 2048 * 2;          // 8 MB
  constexpr size_t oWqT = 0;
  constexpr size_t oWkT = oWqT + DD2;
  constexpr size_t oWvT = oWkT + DD2;
  constexpr size_t oWoT = oWvT + DD2;
  constexpr size_t oW1T = oWoT + DD2;             // 256x2048 bf16 (1 MB)
  constexpr size_t oW2T = oW1T + 256L * 2048 * 2; // 8192x256 bf16 (4 MB)
  constexpr size_t oW3T = oW2T + 8192L * 256 * 2; // 256x8192 bf16 (4 MB)
  constexpr size_t oW4T = oW3T + 256L * 8192 * 2; // 2048x256 bf16 (1 MB)
  constexpr size_t oH1  = oW4T + 2048L * 256 * 2; // 32MB: h1 / kvpart / attnN / rank-partials
  constexpr size_t oQ   = oH1 + 8192L * 2048 * 2; // 32MB: q / h2 / t3f+t3b
  constexpr size_t oKT  = oQ  + 8192L * 2048 * 2; // 32MB: kT / t1
  constexpr size_t oVT  = oKT + 8192L * 2048 * 2; // 32MB: vT / t2chunk
  constexpr size_t oKVT = oVT + 8192L * 2048 * 2; // 64x128x128 bf16 (2MB)
  constexpr size_t oKS  = oKVT + 64L * 128 * 128 * 2;
  constexpr size_t oDEN = oKS + 64L * 128 * 4;

  u16* WqT = (u16*)(ws + oWqT);
  u16* WkT = (u16*)(ws + oWkT);
  u16* WvT = (u16*)(ws + oWvT);
  u16* WoT = (u16*)(ws + oWoT);
  u16* W1T = (u16*)(ws + oW1T);
  u16* W2T = (u16*)(ws + oW2T);
  u16* W3T = (u16*)(ws + oW3T);
  u16* W4T = (u16*)(ws + oW4T);
  u16* H1    = (u16*)(ws + oH1);    // h1; kv partials; attnN; rank split-K partials
  float* KVP = (float*)(ws + oH1);
  float* RP  = (float*)(ws + oH1);  // rank partials [NP][8192][256] f32
  u16* Qb    = (u16*)(ws + oQ);     // q; h2
  float* T3f = (float*)(ws + oQ);   // after h2 dead: t3 f32 (8MB)
  u16* T3B   = (u16*)(ws + oQ + 8L * 1024 * 1024); // t3 bf16 (4MB)
  u16* KT    = (u16*)(ws + oKT);    // kT; then t1
  u16* T1    = (u16*)(ws + oKT);
  u16* VT    = (u16*)(ws + oVT);    // vT; then t2 chunk
  u16* T2C   = (u16*)(ws + oVT);
  u16* KVT = (u16*)(ws + oKVT);
  float* KS  = (float*)(ws + oKS);
  float* DEN = (float*)(ws + oDEN);
  u16* H2  = Qb;

  const dim3 tb32(32, 8);
  tpose_f32_bf16_kernel<<<dim3(64, 64), tb32, 0, stream>>>(Wq, WqT, 2048, 2048);
  tpose_f32_bf16_kernel<<<dim3(64, 64), tb32, 0, stream>>>(Wk, WkT, 2048, 2048);
  tpose_f32_bf16_kernel<<<dim3(64, 64), tb32, 0, stream>>>(Wv, WvT, 2048, 2048);
  tpose_f32_bf16_kernel<<<dim3(64, 64), tb32, 0, stream>>>(Wo, WoT, 2048, 2048);
  tpose_f32_bf16_kernel<<<dim3(8, 64),  tb32, 0, stream>>>(W1, W1T, 2048, 256);
  tpose_f32_bf16_kernel<<<dim3(256, 8), tb32, 0, stream>>>(W2, W2T, 256, 8192);
  tpose_f32_bf16_kernel<<<dim3(8, 256), tb32, 0, stream>>>(W3, W3T, 8192, 256);
  tpose_f32_bf16_kernel<<<dim3(64, 8),  tb32, 0, stream>>>(W4, W4T, 256, 2048);

  // h1 = LN1(x)
  ln_bf16_kernel<<<8192, 256, 0, stream>>>(x, g1, be1, H1);

  // q,k,v projections (256^2 slice-ring, grid 32x8 = 256 blocks)
  btgemm256_kernel<1, 0, 0><<<dim3(32, 8), 512, 0, stream>>>(
      H1, WqT, Qb, bq, nullptr, 2048, 2048, 2048, 2048);
  btgemm256_kernel<1, 2, 0><<<dim3(32, 8), 512, 0, stream>>>(
      H1, WkT, KT, bk, nullptr, 2048, 2048, 2048, 2048);
  btgemm256_kernel<0, 2, 0><<<dim3(32, 8), 512, 0, stream>>>(
      H1, WvT, VT, bv, nullptr, 2048, 2048, 2048, 2048);

  // ksum over S, den = q.ksum
  ksum_kernel<<<2048, 256, 0, stream>>>(KT, KS);
  den_kernel<<<8192, 256, 0, stream>>>(Qb, KS, DEN);

  // kv split-K (z = head*8 + K-chunk of 256) -> f32 partials -> reduce
  btgemm_kernel<0, 1, 0, 0, 0><<<dim3(1, 1, 512), 256, 0, stream>>>(
      VT, KT, KVP, nullptr, nullptr, nullptr, 128, 128, 256, 2048, 2048, 128, 8,
      262144, 256, 262144, 256, 16384, 1048576, 0, 0);
  kvreduce_kernel<<<1024, 256, 0, stream>>>(KVP, KVT);

  // num = q @ kvT ; /(den+eps) -> attnN (bf16, (B,S,D), into H1 region)
  btgemm_kernel<0, 0, 0, 0, 1><<<dim3(16, 1, 64), 256, 0, stream>>>(
      Qb, KVT, H1, nullptr, nullptr, DEN, 2048, 128, 128, 2048, 128, 2048, 16,
      4194304, 128, 262144, 16384, 4194304, 128, 32768, 2048);

  // x2 = x + attnN@Wo + bo -> d_out (f32)
  btgemm256_kernel<0, 1, 1><<<dim3(32, 8), 512, 0, stream>>>(
      H1, WoT, xout, bo, x, 2048, 2048, 2048, 2048);

  // h2 = LN2(x2)
  ln_bf16_kernel<<<8192, 256, 0, stream>>>(xout, g2, be2, H2);

  // t1 = h2@W1 + b1 : split-K x4 (K-sub 512) -> reduce bf16
  btgemm_kernel<0, 1, 0, 0, 0><<<dim3(64, 2, 4), 256, 0, stream>>>(
      H2, W1T, RP, nullptr, nullptr, nullptr, 8192, 256, 512, 2048, 2048, 256, 4,
      0, 512, 0, 512, 0, 2097152, 0, 0);
  rankreduce_kernel<4, 0, 0><<<2048, 256, 0, stream>>>(RP, b1, T1);

  // FFN middle, 4 HID-chunks of 2048:
  //   t2c = gelu(t1@W2c+b2c) [256^2 slice-ring]; t3f (+)= t2c@W3c [split-K x2 + reduce]
  for (int c = 0; c < 4; ++c) {
    btgemm256_kernel<2, 0, 0><<<dim3(32, 8), 512, 0, stream>>>(
        T1, W2T + (long)c * 2048 * 256, T2C, b2 + c * 2048, nullptr,
        256, 256, 256, 2048);
    btgemm_kernel<0, 1, 0, 0, 0><<<dim3(64, 2, 2), 256, 0, stream>>>(
        T2C, W3T + (long)c * 2048, RP, nullptr, nullptr, nullptr,
        8192, 256, 1024, 2048, 8192, 256, 2,
        0, 1024, 0, 1024, 0, 2097152, 0, 0);
    if (c == 0)
      rankreduce_kernel<2, 1, 0><<<2048, 256, 0, stream>>>(RP, b3, T3f);
    else
      rankreduce_kernel<2, 1, 1><<<2048, 256, 0, stream>>>(RP, nullptr, T3f);
  }

  // t3 -> bf16
  cvt_f32_bf16_kernel<<<2048, 256, 0, stream>>>(T3f, T3B, 8192L * 256);

  // out = x2 + t3@W4 + b4   (resid = d_out itself)
  btgemm256_kernel<0, 1, 1><<<dim3(32, 8), 512, 0, stream>>>(
      T3B, W4T, xout, b4, xout, 256, 256, 256, 2048);
}